// Round 10
// baseline (1074.878 us; speedup 1.0000x reference)
//
#include <hip/hip_runtime.h>

typedef unsigned short u16;
typedef __attribute__((ext_vector_type(4))) float f32x4;
typedef __attribute__((ext_vector_type(8))) short s16x8;
typedef __attribute__((ext_vector_type(4))) unsigned short u16x4;
typedef __attribute__((ext_vector_type(8))) unsigned short u16x8;

static __device__ __forceinline__ u16 f2bf(float f) {
    unsigned int x = __float_as_uint(f);
    x += 0x7fffu + ((x >> 16) & 1u);           // round-to-nearest-even
    return (u16)(x >> 16);
}

// ---------------- Stage 1: pooled[b][c] = mean_{h,w} x[b,c,h,w] -------------
__global__ __launch_bounds__(256) void pool_kernel(const float* __restrict__ x,
                                                   float* __restrict__ pooled) {
    int bc = blockIdx.x;
    const float* p = x + (size_t)bc * 3136;
    float s = 0.f;
    for (int i = threadIdx.x; i < 784; i += 256) {       // 784*4 = 3136
        f32x4 v = *(const f32x4*)(p + i * 4);
        s += v.x + v.y + v.z + v.w;
    }
#pragma unroll
    for (int off = 32; off; off >>= 1) s += __shfl_xor(s, off);
    __shared__ float red[4];
    int lane = threadIdx.x & 63, wave = threadIdx.x >> 6;
    if (lane == 0) red[wave] = s;
    __syncthreads();
    if (threadIdx.x == 0)
        pooled[bc] = (red[0] + red[1] + red[2] + red[3]) * (1.0f / 3136.0f);
}

// ---------------- Stage 2: h[b][i] = relu(sum_j pooled[b][j]*fc1_w[i][j]) ---
__global__ __launch_bounds__(256) void fc1_kernel(const float* __restrict__ pooled,
                                                  const float* __restrict__ w,
                                                  float* __restrict__ h) {
    __shared__ float pv[256];
    int b = blockIdx.x >> 6;
    pv[threadIdx.x] = pooled[b * 256 + threadIdx.x];
    __syncthreads();
    int lane = threadIdx.x & 63, wave = threadIdx.x >> 6;
    int i = ((blockIdx.x & 63) << 2) + wave;
    f32x4 v = *(const f32x4*)(w + i * 256 + lane * 4);
    float s = v.x * pv[lane * 4 + 0] + v.y * pv[lane * 4 + 1] +
              v.z * pv[lane * 4 + 2] + v.w * pv[lane * 4 + 3];
#pragma unroll
    for (int off = 32; off; off >>= 1) s += __shfl_xor(s, off);
    if (lane == 0) h[b * 256 + i] = fmaxf(s, 0.f);
}

// ---------------- Stage 3: kern[b][oc] = sum_j h[b][j]*fc2_w[oc][j] + b -----
__global__ __launch_bounds__(256) void fc2_kernel(const float* __restrict__ h,
                                                  const float* __restrict__ w,
                                                  const float* __restrict__ bias,
                                                  float* __restrict__ kern) {
    __shared__ float hv[256];
    int b = blockIdx.x >> 8;
    hv[threadIdx.x] = h[b * 256 + threadIdx.x];
    __syncthreads();
    int lane = threadIdx.x & 63, wave = threadIdx.x >> 6;
    int i = ((blockIdx.x & 255) << 2) + wave;
    f32x4 v = *(const f32x4*)(w + i * 256 + lane * 4);
    float s = v.x * hv[lane * 4 + 0] + v.y * hv[lane * 4 + 1] +
              v.z * hv[lane * 4 + 2] + v.w * hv[lane * 4 + 3];
#pragma unroll
    for (int off = 32; off; off >>= 1) s += __shfl_xor(s, off);
    if (lane == 0) kern[b * 1024 + i] = s + bias[i];
}

// ---------------- Stage 4: dynw[b][o][p][c] = bf16(sigmoid(cw)*weight) -----
__global__ __launch_bounds__(256) void dynw_kernel(const float* __restrict__ kern,
                                                   const float* __restrict__ cogw,
                                                   const float* __restrict__ wgt,
                                                   u16* __restrict__ dynw) {
    __shared__ float wl[2304];                  // wgt[o][256 c][9 p]
    const int o = blockIdx.x & 255;
    const int bg = blockIdx.x >> 8;             // 0..3 -> 8 batches each
    const int c = threadIdx.x;
    const float* wo = wgt + (size_t)o * 2304;
#pragma unroll
    for (int j = 0; j < 9; ++j)                 // fully coalesced
        wl[j * 256 + c] = wo[j * 256 + c];
    __syncthreads();

    float cg0[9], cg1[9], cg2[9], cg3[9];       // cog[o][t][p] — wave-uniform
#pragma unroll
    for (int p = 0; p < 9; ++p) {
        cg0[p] = cogw[(o * 4 + 0) * 9 + p];
        cg1[p] = cogw[(o * 4 + 1) * 9 + p];
        cg2[p] = cogw[(o * 4 + 2) * 9 + p];
        cg3[p] = cogw[(o * 4 + 3) * 9 + p];
    }
    float w9[9];                                // stride-9 LDS read: odd -> conflict-free
#pragma unroll
    for (int p = 0; p < 9; ++p) w9[p] = wl[c * 9 + p];

    for (int b = bg * 8; b < bg * 8 + 8; ++b) {
        f32x4 k4 = *(const f32x4*)(kern + b * 1024 + c * 4);
        u16* dst = dynw + (size_t)(b * 256 + o) * 9 * 256 + c;
#pragma unroll
        for (int p = 0; p < 9; ++p) {
            float cw = k4.x * cg0[p] + k4.y * cg1[p] + k4.z * cg2[p] + k4.w * cg3[p];
            float sg = 1.0f / (1.0f + __expf(-cw));
            dst[p * 256] = f2bf(sg * w9[p]);    // coalesced per (b,p)
        }
    }
}

// ---------------- Stage 4.5: xT[b][y][x][c] = bf16(x[b][c][y-1][x-1]) ------
// Padded 58x58 spatial, zero borders (conv halo baked in). c innermost so a
// conv B-frag (8 consecutive c) is one global_load_dwordx4, and the 4 quads
// of each l15 share one 64B segment.
// grid = 32 b * 58 y * 4 cg = 7424 blocks.
__global__ __launch_bounds__(256) void xpose_kernel(const float* __restrict__ x,
                                                    u16* __restrict__ xT) {
    const int gid = blockIdx.x;
    const int cg = gid & 3;                     // 64-c group
    const int yp = (gid >> 2) % 58;             // padded y
    const int b = gid / (4 * 58);
    u16* dst = xT + ((size_t)b * 58 + yp) * 58 * 256 + cg * 64;
    const int t = threadIdx.x;

    if (yp == 0 || yp == 57) {                  // block-uniform branch
        for (int i = t; i < 464; i += 256) {    // 58 x * 64 c / 8
            int xcol = i >> 3, k = i & 7;
            *(u16x8*)(dst + (size_t)xcol * 256 + k * 8) = (u16x8)(0);
        }
        return;
    }
    __shared__ float tile[64][57];              // +1 pad
    const float* src = x + ((size_t)(b * 256 + cg * 64) * 56 + (yp - 1)) * 56;
    for (int i = t; i < 64 * 56; i += 256) {
        int cr = i / 56, xcol = i - cr * 56;
        tile[cr][xcol] = src[(size_t)cr * 3136 + xcol];
    }
    if (t < 16) {                               // x-border zeros (x=0 and 57)
        int side = t >> 3, k = t & 7;
        *(u16x8*)(dst + (size_t)(side ? 57 : 0) * 256 + k * 8) = (u16x8)(0);
    }
    __syncthreads();
    for (int i = t; i < 896; i += 256) {        // 56 x * 16 c4-groups
        int xcol = i >> 4, c4 = i & 15;
        u16x4 v;
        v.x = f2bf(tile[c4 * 4 + 0][xcol]);
        v.y = f2bf(tile[c4 * 4 + 1][xcol]);
        v.z = f2bf(tile[c4 * 4 + 2][xcol]);
        v.w = f2bf(tile[c4 * 4 + 3][xcol]);
        *(u16x4*)(dst + (size_t)(xcol + 1) * 256 + c4 * 4) = v;
    }
}

// ---------------- Stage 5: conv, NO LDS / NO barriers ----------------------
// v6: B-fragments read directly from xT (b128, 16 fully-used 64B segments
// per wave-load); A from dynw as before. v3's tile/mapping/epilogue kept:
// block 128o x 112s, 4 waves, wave 32o x 112s, acc[2][7]. The entire
// stage+cvt+barrier apparatus is gone; latency hidden by vmcnt pipelining
// and 4 waves/SIMD (acc 56 + arch ~70 fits the 128 budget).
__global__ __launch_bounds__(256, 4) void conv_kernel(const u16* __restrict__ xT,
                                                      const u16* __restrict__ dynw,
                                                      float* __restrict__ out) {
    const int tid = threadIdx.x;
    const int wave = tid >> 6, lane = tid & 63;
    const int l15 = lane & 15, quad = lane >> 4;
    const int gid = blockIdx.x;
    const int slot = gid >> 3;                  // 0..223
    const int b = (gid & 7) * 4 + slot / 56;    // same-XCD blocks share b-slabs
    const int s2 = slot % 56;
    const int stile = s2 >> 1;                  // 0..27
    const int oh = s2 & 1;                      // o-half 0/1
    const int y0 = stile * 2;

    f32x4 acc[2][7];
#pragma unroll
    for (int mf = 0; mf < 2; ++mf)
#pragma unroll
        for (int nf = 0; nf < 7; ++nf) acc[mf][nf] = (f32x4){0.f, 0.f, 0.f, 0.f};

    // per-nf padded (y,x) cell index; B addr = (cell + dy*58 + dx)*256 u16
    int rowcol[7];
#pragma unroll
    for (int nf = 0; nf < 7; ++nf) {
        int n = nf * 16 + l15;                  // s within the 112-tile
        int r = (n >= 56) ? 1 : 0;
        int xx = n - 56 * r;
        rowcol[nf] = (y0 + r) * 58 + xx;        // (y0+r-1+dy)+1 = y0+r+dy
    }
    const u16* Bbase = xT + (size_t)b * 58 * 58 * 256 + quad * 8;
    const u16* Abase = dynw + ((size_t)b * 256 + oh * 128 + wave * 32 + l15) * 2304 + quad * 8;

#pragma unroll 1
    for (int cc = 0; cc < 8; ++cc) {
#pragma unroll
        for (int dy = 0; dy < 3; ++dy) {
#pragma unroll
            for (int dx = 0; dx < 3; ++dx) {
                const int p = dy * 3 + dx;
                s16x8 a0 = *(const s16x8*)(Abase + 0 * 36864 + p * 256 + cc * 32);
                s16x8 a1 = *(const s16x8*)(Abase + 1 * 36864 + p * 256 + cc * 32);
#pragma unroll
                for (int nf = 0; nf < 7; ++nf) {
                    const u16* bp = Bbase + ((size_t)(rowcol[nf] + dy * 58 + dx) << 8) + cc * 32;
                    s16x8 bf = *(const s16x8*)bp;
                    acc[0][nf] = __builtin_amdgcn_mfma_f32_16x16x32_bf16(a0, bf, acc[0][nf], 0, 0, 0);
                    acc[1][nf] = __builtin_amdgcn_mfma_f32_16x16x32_bf16(a1, bf, acc[1][nf], 0, 0, 0);
                }
            }
        }
    }
    // epilogue: D[row=quad*4+r][col=l15] (m89/m91-verified C/D layout)
#pragma unroll
    for (int mf = 0; mf < 2; ++mf) {
        int o = oh * 128 + wave * 32 + mf * 16 + quad * 4;
        size_t obase = ((size_t)b * 256 + o) * 3136 + (size_t)stile * 112 + l15;
#pragma unroll
        for (int nf = 0; nf < 7; ++nf) {
#pragma unroll
            for (int r = 0; r < 4; ++r)
                out[obase + (size_t)r * 3136 + nf * 16] = acc[mf][nf][r];
        }
    }
}

extern "C" void kernel_launch(void* const* d_in, const int* in_sizes, int n_in,
                              void* d_out, int out_size, void* d_ws, size_t ws_size,
                              hipStream_t stream) {
    const float* x    = (const float*)d_in[0];   // [32,256,56,56] f32
    const float* fc1w = (const float*)d_in[1];   // [256,256]
    const float* fc2w = (const float*)d_in[2];   // [1024,256]
    const float* fc2b = (const float*)d_in[3];   // [1024]
    const float* cogw = (const float*)d_in[4];   // [256,4,3,3]
    const float* wgt  = (const float*)d_in[5];   // [256,256,3,3]
    float* out = (float*)d_out;                  // [32,256,56,56] f32

    char* ws = (char*)d_ws;
    float* pooled = (float*)ws;                  // 32 KB
    float* h      = (float*)(ws + 32768);        // 32 KB
    float* kern   = (float*)(ws + 65536);        // 128 KB
    u16*   dynw   = (u16*)(ws + 196608);         // 37.75 MB, [b][o][p][c] bf16
    u16*   xT     = (u16*)(ws + 37945344);       // 55.1 MB, [b][58][58][256] bf16

    xpose_kernel<<<7424, 256, 0, stream>>>(x, xT);
    pool_kernel<<<8192, 256, 0, stream>>>(x, pooled);
    fc1_kernel<<<2048, 256, 0, stream>>>(pooled, fc1w, h);
    fc2_kernel<<<8192, 256, 0, stream>>>(h, fc2w, fc2b, kern);
    dynw_kernel<<<1024, 256, 0, stream>>>(kern, cogw, wgt, dynw);
    conv_kernel<<<1792, 256, 0, stream>>>(xT, dynw, out);
}

// Round 11
// 403.448 us; speedup vs baseline: 2.6642x; 2.6642x over previous
//
#include <hip/hip_runtime.h>

typedef unsigned short u16;
typedef __attribute__((ext_vector_type(4))) float f32x4;
typedef __attribute__((ext_vector_type(8))) short s16x8;
typedef __attribute__((ext_vector_type(4))) unsigned short u16x4;

static __device__ __forceinline__ u16 f2bf(float f) {
    unsigned int x = __float_as_uint(f);
    x += 0x7fffu + ((x >> 16) & 1u);           // round-to-nearest-even
    return (u16)(x >> 16);
}

// ---------------- Stage 1: pooled[b][c] = mean_{h,w} x[b,c,h,w] -------------
__global__ __launch_bounds__(256) void pool_kernel(const float* __restrict__ x,
                                                   float* __restrict__ pooled) {
    int bc = blockIdx.x;
    const float* p = x + (size_t)bc * 3136;
    float s = 0.f;
    for (int i = threadIdx.x; i < 784; i += 256) {       // 784*4 = 3136
        f32x4 v = *(const f32x4*)(p + i * 4);
        s += v.x + v.y + v.z + v.w;
    }
#pragma unroll
    for (int off = 32; off; off >>= 1) s += __shfl_xor(s, off);
    __shared__ float red[4];
    int lane = threadIdx.x & 63, wave = threadIdx.x >> 6;
    if (lane == 0) red[wave] = s;
    __syncthreads();
    if (threadIdx.x == 0)
        pooled[bc] = (red[0] + red[1] + red[2] + red[3]) * (1.0f / 3136.0f);
}

// ---------------- Stage 2: h[b][i] = relu(sum_j pooled[b][j]*fc1_w[i][j]) ---
__global__ __launch_bounds__(256) void fc1_kernel(const float* __restrict__ pooled,
                                                  const float* __restrict__ w,
                                                  float* __restrict__ h) {
    __shared__ float pv[256];
    int b = blockIdx.x >> 6;
    pv[threadIdx.x] = pooled[b * 256 + threadIdx.x];
    __syncthreads();
    int lane = threadIdx.x & 63, wave = threadIdx.x >> 6;
    int i = ((blockIdx.x & 63) << 2) + wave;
    f32x4 v = *(const f32x4*)(w + i * 256 + lane * 4);
    float s = v.x * pv[lane * 4 + 0] + v.y * pv[lane * 4 + 1] +
              v.z * pv[lane * 4 + 2] + v.w * pv[lane * 4 + 3];
#pragma unroll
    for (int off = 32; off; off >>= 1) s += __shfl_xor(s, off);
    if (lane == 0) h[b * 256 + i] = fmaxf(s, 0.f);
}

// ---------------- Stage 3: kern[b][oc] = sum_j h[b][j]*fc2_w[oc][j] + b -----
__global__ __launch_bounds__(256) void fc2_kernel(const float* __restrict__ h,
                                                  const float* __restrict__ w,
                                                  const float* __restrict__ bias,
                                                  float* __restrict__ kern) {
    __shared__ float hv[256];
    int b = blockIdx.x >> 8;
    hv[threadIdx.x] = h[b * 256 + threadIdx.x];
    __syncthreads();
    int lane = threadIdx.x & 63, wave = threadIdx.x >> 6;
    int i = ((blockIdx.x & 255) << 2) + wave;
    f32x4 v = *(const f32x4*)(w + i * 256 + lane * 4);
    float s = v.x * hv[lane * 4 + 0] + v.y * hv[lane * 4 + 1] +
              v.z * hv[lane * 4 + 2] + v.w * hv[lane * 4 + 3];
#pragma unroll
    for (int off = 32; off; off >>= 1) s += __shfl_xor(s, off);
    if (lane == 0) kern[b * 1024 + i] = s + bias[i];
}

// ---------------- Stage 4: dynw[b][o][p][c] = bf16(sigmoid(cw)*weight) -----
__global__ __launch_bounds__(256) void dynw_kernel(const float* __restrict__ kern,
                                                   const float* __restrict__ cogw,
                                                   const float* __restrict__ wgt,
                                                   u16* __restrict__ dynw) {
    __shared__ float wl[2304];                  // wgt[o][256 c][9 p]
    const int o = blockIdx.x & 255;
    const int bg = blockIdx.x >> 8;             // 0..3 -> 8 batches each
    const int c = threadIdx.x;
    const float* wo = wgt + (size_t)o * 2304;
#pragma unroll
    for (int j = 0; j < 9; ++j)                 // fully coalesced
        wl[j * 256 + c] = wo[j * 256 + c];
    __syncthreads();

    float cg0[9], cg1[9], cg2[9], cg3[9];       // cog[o][t][p] — wave-uniform
#pragma unroll
    for (int p = 0; p < 9; ++p) {
        cg0[p] = cogw[(o * 4 + 0) * 9 + p];
        cg1[p] = cogw[(o * 4 + 1) * 9 + p];
        cg2[p] = cogw[(o * 4 + 2) * 9 + p];
        cg3[p] = cogw[(o * 4 + 3) * 9 + p];
    }
    float w9[9];                                // stride-9 LDS read: odd -> conflict-free
#pragma unroll
    for (int p = 0; p < 9; ++p) w9[p] = wl[c * 9 + p];

    for (int b = bg * 8; b < bg * 8 + 8; ++b) {
        f32x4 k4 = *(const f32x4*)(kern + b * 1024 + c * 4);
        u16* dst = dynw + (size_t)(b * 256 + o) * 9 * 256 + c;
#pragma unroll
        for (int p = 0; p < 9; ++p) {
            float cw = k4.x * cg0[p] + k4.y * cg1[p] + k4.z * cg2[p] + k4.w * cg3[p];
            float sg = 1.0f / (1.0f + __expf(-cw));
            dst[p * 256] = f2bf(sg * w9[p]);    // coalesced per (b,p)
        }
    }
}

// ---------------- Stage 5: per-sample conv via implicit GEMM + MFMA --------
// v7 = v3 staging/layout + v4's H-collapse reads + DIRECT scattered stores.
// n-mapping: n(l15,nf) = l15*7 + nf -> lane's 7 nf are consecutive s; per dy
// one H[0..8] read block (9 b128) feeds all 21 (dx,nf) MFMA pairs:
// 27 reads/wave/cc vs v3's 63 (the measured LDS-pipe is the v3 limiter).
// v4's costs removed: no transpose epilogue (stores go direct; each 64B
// out-line is fully covered by one wave's 7 nf-stores -> L2 write-combines),
// no extra LDS (18,560 B), no extra barriers. Staging byte-identical to v3.
#define LDSW 40
__global__ __launch_bounds__(256, 3) void conv_kernel(const float* __restrict__ x,
                                                      const u16* __restrict__ dynw,
                                                      float* __restrict__ out) {
    __shared__ u16 lds[4 * 58 * LDSW];          // 18,560 B
    const int tid = threadIdx.x;
    const int wave = tid >> 6, lane = tid & 63;
    const int l15 = lane & 15, quad = lane >> 4;
    const int gid = blockIdx.x;
    const int slot = gid >> 3;                  // 0..223
    const int b = (gid & 7) * 4 + slot / 56;    // same-XCD blocks share b-slabs
    const int s2 = slot % 56;
    const int stile = s2 >> 1;                  // 0..27
    const int oh = s2 & 1;                      // o-half 0/1
    const int y0 = stile * 2;

    // zero halo columns col=0 and col=57 once (valid for every chunk)
    if (tid < 64) {
        int side = tid & 1, yy = (tid >> 1) & 3, cg = tid >> 3;
        *(u16x4*)&lds[(yy * 58 + (side ? 57 : 0)) * LDSW + cg * 4] = (u16x4){0, 0, 0, 0};
    }

    f32x4 acc[2][7];
#pragma unroll
    for (int mf = 0; mf < 2; ++mf)
#pragma unroll
        for (int nf = 0; nf < 7; ++nf) acc[mf][nf] = (f32x4){0.f, 0.f, 0.f, 0.f};

    // per-lane H base: n0 = l15*7 -> (row r0, col xx0); H[t] at padded col xx0+t
    const int n0 = l15 * 7;
    const int r0 = (n0 >= 56) ? 1 : 0;
    const int xx0 = n0 - 56 * r0;
    const int hbase = (r0 * 58 + xx0) * LDSW + quad * 8;

    const u16* Abase = dynw + ((size_t)b * 256 + oh * 128 + wave * 32 + l15) * 2304 + quad * 8;
    const float* Xb = x + (size_t)b * 256 * 3136;

    __syncthreads();
    for (int cc = 0; cc < 8; ++cc) {
        // stage 32 c x 4 rows x 56 cols: 4 plane-strided loads -> one b64 write
#pragma unroll
        for (int it = 0; it < 7; ++it) {
            int i = it * 256 + tid;             // 1792 = 8 cg * 4 yy * 56 xx
            int q = i / 56;
            int xx = i - q * 56;
            int yy = q & 3;
            int cg = q >> 2;
            int yg = y0 - 1 + yy;
            u16x4 w = (u16x4){0, 0, 0, 0};
            if ((unsigned)yg < 56u) {
                const float* src = Xb + (size_t)(cc * 32 + cg * 4) * 3136 + yg * 56 + xx;
                w.x = f2bf(src[0]);
                w.y = f2bf(src[3136]);
                w.z = f2bf(src[2 * 3136]);
                w.w = f2bf(src[3 * 3136]);
            }
            *(u16x4*)&lds[(yy * 58 + 1 + xx) * LDSW + cg * 4] = w;   // 8B-aligned
        }
        __syncthreads();
#pragma unroll
        for (int dy = 0; dy < 3; ++dy) {
            s16x8 H[9];                         // shared across the 3 dx taps
#pragma unroll
            for (int t = 0; t < 9; ++t)
                H[t] = *(const s16x8*)(&lds[hbase + (dy * 58 + t) * LDSW]);
#pragma unroll
            for (int dx = 0; dx < 3; ++dx) {
                const int p = dy * 3 + dx;
                s16x8 a0 = *(const s16x8*)(Abase + 0 * 36864 + p * 256 + cc * 32);
                s16x8 a1 = *(const s16x8*)(Abase + 1 * 36864 + p * 256 + cc * 32);
#pragma unroll
                for (int nf = 0; nf < 7; ++nf) {
                    acc[0][nf] = __builtin_amdgcn_mfma_f32_16x16x32_bf16(a0, H[nf + dx], acc[0][nf], 0, 0, 0);
                    acc[1][nf] = __builtin_amdgcn_mfma_f32_16x16x32_bf16(a1, H[nf + dx], acc[1][nf], 0, 0, 0);
                }
            }
        }
        __syncthreads();
    }

    // epilogue: direct stores. C/D col = l15 -> s = l15*7 + nf; row=quad*4+r -> o.
    // Each 64B out-line is covered by one wave's nf-unrolled stores -> L2 combines.
#pragma unroll
    for (int mf = 0; mf < 2; ++mf) {
        int o = oh * 128 + wave * 32 + mf * 16 + quad * 4;
        size_t obase = ((size_t)b * 256 + o) * 3136 + (size_t)stile * 112 + l15 * 7;
#pragma unroll
        for (int nf = 0; nf < 7; ++nf) {
#pragma unroll
            for (int r = 0; r < 4; ++r)
                out[obase + (size_t)r * 3136 + nf] = acc[mf][nf][r];
        }
    }
}

extern "C" void kernel_launch(void* const* d_in, const int* in_sizes, int n_in,
                              void* d_out, int out_size, void* d_ws, size_t ws_size,
                              hipStream_t stream) {
    const float* x    = (const float*)d_in[0];   // [32,256,56,56] f32
    const float* fc1w = (const float*)d_in[1];   // [256,256]
    const float* fc2w = (const float*)d_in[2];   // [1024,256]
    const float* fc2b = (const float*)d_in[3];   // [1024]
    const float* cogw = (const float*)d_in[4];   // [256,4,3,3]
    const float* wgt  = (const float*)d_in[5];   // [256,256,3,3]
    float* out = (float*)d_out;                  // [32,256,56,56] f32

    char* ws = (char*)d_ws;
    float* pooled = (float*)ws;              // 32 KB
    float* h      = (float*)(ws + 32768);    // 32 KB
    float* kern   = (float*)(ws + 65536);    // 128 KB
    u16*   dynw   = (u16*)(ws + 196608);     // 37.75 MB, [b][o][p][c] bf16

    pool_kernel<<<8192, 256, 0, stream>>>(x, pooled);
    fc1_kernel<<<2048, 256, 0, stream>>>(pooled, fc1w, h);
    fc2_kernel<<<8192, 256, 0, stream>>>(h, fc2w, fc2b, kern);
    dynw_kernel<<<1024, 256, 0, stream>>>(kern, cogw, wgt, dynw);
    conv_kernel<<<1792, 256, 0, stream>>>(x, dynw, out);
}

// Round 13
// 372.587 us; speedup vs baseline: 2.8849x; 1.0828x over previous
//
#include <hip/hip_runtime.h>

typedef unsigned short u16;
typedef __attribute__((ext_vector_type(4))) float f32x4;
typedef __attribute__((ext_vector_type(8))) short s16x8;
typedef __attribute__((ext_vector_type(4))) unsigned short u16x4;

static __device__ __forceinline__ u16 f2bf(float f) {
    unsigned int x = __float_as_uint(f);
    x += 0x7fffu + ((x >> 16) & 1u);           // round-to-nearest-even
    return (u16)(x >> 16);
}

// ---------------- Stage 1: pooled[b][c] = mean_{h,w} x[b,c,h,w] -------------
__global__ __launch_bounds__(256) void pool_kernel(const float* __restrict__ x,
                                                   float* __restrict__ pooled) {
    int bc = blockIdx.x;
    const float* p = x + (size_t)bc * 3136;
    float s = 0.f;
    for (int i = threadIdx.x; i < 784; i += 256) {       // 784*4 = 3136
        f32x4 v = *(const f32x4*)(p + i * 4);
        s += v.x + v.y + v.z + v.w;
    }
#pragma unroll
    for (int off = 32; off; off >>= 1) s += __shfl_xor(s, off);
    __shared__ float red[4];
    int lane = threadIdx.x & 63, wave = threadIdx.x >> 6;
    if (lane == 0) red[wave] = s;
    __syncthreads();
    if (threadIdx.x == 0)
        pooled[bc] = (red[0] + red[1] + red[2] + red[3]) * (1.0f / 3136.0f);
}

// ---------------- Stage 2: h[b][i] = relu(sum_j pooled[b][j]*fc1_w[i][j]) ---
__global__ __launch_bounds__(256) void fc1_kernel(const float* __restrict__ pooled,
                                                  const float* __restrict__ w,
                                                  float* __restrict__ h) {
    __shared__ float pv[256];
    int b = blockIdx.x >> 6;
    pv[threadIdx.x] = pooled[b * 256 + threadIdx.x];
    __syncthreads();
    int lane = threadIdx.x & 63, wave = threadIdx.x >> 6;
    int i = ((blockIdx.x & 63) << 2) + wave;
    f32x4 v = *(const f32x4*)(w + i * 256 + lane * 4);
    float s = v.x * pv[lane * 4 + 0] + v.y * pv[lane * 4 + 1] +
              v.z * pv[lane * 4 + 2] + v.w * pv[lane * 4 + 3];
#pragma unroll
    for (int off = 32; off; off >>= 1) s += __shfl_xor(s, off);
    if (lane == 0) h[b * 256 + i] = fmaxf(s, 0.f);
}

// ---------------- Stage 3: kern[b][oc] = sum_j h[b][j]*fc2_w[oc][j] + b -----
__global__ __launch_bounds__(256) void fc2_kernel(const float* __restrict__ h,
                                                  const float* __restrict__ w,
                                                  const float* __restrict__ bias,
                                                  float* __restrict__ kern) {
    __shared__ float hv[256];
    int b = blockIdx.x >> 8;
    hv[threadIdx.x] = h[b * 256 + threadIdx.x];
    __syncthreads();
    int lane = threadIdx.x & 63, wave = threadIdx.x >> 6;
    int i = ((blockIdx.x & 255) << 2) + wave;
    f32x4 v = *(const f32x4*)(w + i * 256 + lane * 4);
    float s = v.x * hv[lane * 4 + 0] + v.y * hv[lane * 4 + 1] +
              v.z * hv[lane * 4 + 2] + v.w * hv[lane * 4 + 3];
#pragma unroll
    for (int off = 32; off; off >>= 1) s += __shfl_xor(s, off);
    if (lane == 0) kern[b * 1024 + i] = s + bias[i];
}

// ---------------- Stage 4: dynw[b][o][p][c] = bf16(sigmoid(cw)*weight) -----
__global__ __launch_bounds__(256) void dynw_kernel(const float* __restrict__ kern,
                                                   const float* __restrict__ cogw,
                                                   const float* __restrict__ wgt,
                                                   u16* __restrict__ dynw) {
    __shared__ float wl[2304];                  // wgt[o][256 c][9 p]
    const int o = blockIdx.x & 255;
    const int bg = blockIdx.x >> 8;             // 0..3 -> 8 batches each
    const int c = threadIdx.x;
    const float* wo = wgt + (size_t)o * 2304;
#pragma unroll
    for (int j = 0; j < 9; ++j)                 // fully coalesced
        wl[j * 256 + c] = wo[j * 256 + c];
    __syncthreads();

    float cg0[9], cg1[9], cg2[9], cg3[9];       // cog[o][t][p] — wave-uniform
#pragma unroll
    for (int p = 0; p < 9; ++p) {
        cg0[p] = cogw[(o * 4 + 0) * 9 + p];
        cg1[p] = cogw[(o * 4 + 1) * 9 + p];
        cg2[p] = cogw[(o * 4 + 2) * 9 + p];
        cg3[p] = cogw[(o * 4 + 3) * 9 + p];
    }
    float w9[9];                                // stride-9 LDS read: odd -> conflict-free
#pragma unroll
    for (int p = 0; p < 9; ++p) w9[p] = wl[c * 9 + p];

    for (int b = bg * 8; b < bg * 8 + 8; ++b) {
        f32x4 k4 = *(const f32x4*)(kern + b * 1024 + c * 4);
        u16* dst = dynw + (size_t)(b * 256 + o) * 9 * 256 + c;
#pragma unroll
        for (int p = 0; p < 9; ++p) {
            float cw = k4.x * cg0[p] + k4.y * cg1[p] + k4.z * cg2[p] + k4.w * cg3[p];
            float sg = 1.0f / (1.0f + __expf(-cw));
            dst[p * 256] = f2bf(sg * w9[p]);    // coalesced per (b,p)
        }
    }
}

// ---------------- Stage 5: per-sample conv via implicit GEMM + MFMA --------
// v8 (fixed) = v3 per-wave structure, 512-thread blocks (8 waves, 256o tile).
// Evidence (v1/v3/v4/v5/v7): conv time tracks occupancy, NOT LDS-read count.
// Occupancy 40% -> 50% (launch_bounds(512,4): 2 blocks/CU = 16 waves/CU) AND
// per-wave staging halved (1792 cells shared by 8 waves; oh-split removed).
// A/epilogue pairing is v3's verified scheme: wave w owns o in [w*32,w*32+32);
// a0 = Abase + 0*36864 (o rows w*32..+15), a1 = Abase + 1*36864 (+16..+31);
// epilogue o = wave*32 + mf*16 + quad*4. (36864 u16 = 16 o-rows x 2304.)
// Registers: 64 arch (v3-measured, same inner code) + 56 acc = 120 <= 128.
#define LDSW 40
__global__ __launch_bounds__(512, 4) void conv_kernel(const float* __restrict__ x,
                                                      const u16* __restrict__ dynw,
                                                      float* __restrict__ out) {
    __shared__ u16 lds[4 * 58 * LDSW];          // 18,560 B
    const int tid = threadIdx.x;
    const int wave = tid >> 6, lane = tid & 63;
    const int l15 = lane & 15, quad = lane >> 4;
    const int gid = blockIdx.x;
    const int slot = gid >> 3;                  // 0..111
    const int b = (gid & 7) * 4 + slot / 28;    // same-XCD blocks share b-slabs
    const int stile = slot % 28;                // 0..27
    const int y0 = stile * 2;

    // zero halo columns col=0 and col=57 once (valid for every chunk)
    if (tid < 64) {
        int side = tid & 1, yy = (tid >> 1) & 3, cg = tid >> 3;
        *(u16x4*)&lds[(yy * 58 + (side ? 57 : 0)) * LDSW + cg * 4] = (u16x4){0, 0, 0, 0};
    }

    f32x4 acc[2][7];
#pragma unroll
    for (int mf = 0; mf < 2; ++mf)
#pragma unroll
        for (int nf = 0; nf < 7; ++nf) acc[mf][nf] = (f32x4){0.f, 0.f, 0.f, 0.f};

    int bbase[7];
#pragma unroll
    for (int nf = 0; nf < 7; ++nf) {
        int n = nf * 16 + l15;                  // s within the 112-tile
        int r = (n >= 56) ? 1 : 0;
        int xx = n - 56 * r;
        bbase[nf] = (r * 58 + xx) * LDSW + quad * 8;
    }
    const u16* Abase = dynw + ((size_t)b * 256 + wave * 32 + l15) * 2304 + quad * 8;
    const float* Xb = x + (size_t)b * 256 * 3136;

    __syncthreads();
    for (int cc = 0; cc < 8; ++cc) {
        // stage 32 c x 4 rows x 56 cols: 1792 cells / 512 thr = 3.5 iters
#pragma unroll
        for (int it = 0; it < 4; ++it) {
            int i = it * 512 + tid;
            if (i < 1792) {                     // it=3: half-block tail
                int q = i / 56;
                int xx = i - q * 56;
                int yy = q & 3;
                int cg = q >> 2;
                int yg = y0 - 1 + yy;
                u16x4 w = (u16x4){0, 0, 0, 0};
                if ((unsigned)yg < 56u) {
                    const float* src = Xb + (size_t)(cc * 32 + cg * 4) * 3136 + yg * 56 + xx;
                    w.x = f2bf(src[0]);
                    w.y = f2bf(src[3136]);
                    w.z = f2bf(src[2 * 3136]);
                    w.w = f2bf(src[3 * 3136]);
                }
                *(u16x4*)&lds[(yy * 58 + 1 + xx) * LDSW + cg * 4] = w;   // 8B-aligned
            }
        }
        __syncthreads();
#pragma unroll
        for (int p = 0; p < 9; ++p) {
            const int dy = p / 3, dx = p % 3;
            const int tapoff = (dy * 58 + dx) * LDSW;
            s16x8 a0 = *(const s16x8*)(Abase + 0 * 36864 + p * 256 + cc * 32);
            s16x8 a1 = *(const s16x8*)(Abase + 1 * 36864 + p * 256 + cc * 32);
#pragma unroll
            for (int nf = 0; nf < 7; ++nf) {
                s16x8 bf = *(const s16x8*)(&lds[bbase[nf] + tapoff]);
                acc[0][nf] = __builtin_amdgcn_mfma_f32_16x16x32_bf16(a0, bf, acc[0][nf], 0, 0, 0);
                acc[1][nf] = __builtin_amdgcn_mfma_f32_16x16x32_bf16(a1, bf, acc[1][nf], 0, 0, 0);
            }
        }
        __syncthreads();
    }
    // epilogue: D[row=quad*4+r][col=l15] (m89/m91-verified C/D layout)
#pragma unroll
    for (int mf = 0; mf < 2; ++mf) {
        int o = wave * 32 + mf * 16 + quad * 4;
        size_t obase = ((size_t)b * 256 + o) * 3136 + (size_t)stile * 112 + l15;
#pragma unroll
        for (int nf = 0; nf < 7; ++nf) {
#pragma unroll
            for (int r = 0; r < 4; ++r)
                out[obase + (size_t)r * 3136 + nf * 16] = acc[mf][nf][r];
        }
    }
}

extern "C" void kernel_launch(void* const* d_in, const int* in_sizes, int n_in,
                              void* d_out, int out_size, void* d_ws, size_t ws_size,
                              hipStream_t stream) {
    const float* x    = (const float*)d_in[0];   // [32,256,56,56] f32
    const float* fc1w = (const float*)d_in[1];   // [256,256]
    const float* fc2w = (const float*)d_in[2];   // [1024,256]
    const float* fc2b = (const float*)d_in[3];   // [1024]
    const float* cogw = (const float*)d_in[4];   // [256,4,3,3]
    const float* wgt  = (const float*)d_in[5];   // [256,256,3,3]
    float* out = (float*)d_out;                  // [32,256,56,56] f32

    char* ws = (char*)d_ws;
    float* pooled = (float*)ws;              // 32 KB
    float* h      = (float*)(ws + 32768);    // 32 KB
    float* kern   = (float*)(ws + 65536);    // 128 KB
    u16*   dynw   = (u16*)(ws + 196608);     // 37.75 MB, [b][o][p][c] bf16

    pool_kernel<<<8192, 256, 0, stream>>>(x, pooled);
    fc1_kernel<<<2048, 256, 0, stream>>>(pooled, fc1w, h);
    fc2_kernel<<<8192, 256, 0, stream>>>(h, fc2w, fc2b, kern);
    dynw_kernel<<<1024, 256, 0, stream>>>(kern, cogw, wgt, dynw);
    conv_kernel<<<896, 512, 0, stream>>>(x, dynw, out);
}